// Round 1
// baseline (177.237 us; speedup 1.0000x reference)
//
#include <hip/hip_runtime.h>

// SparseConv1x1: out[n,o,h,w] = sum_i W[o,i]*x[n,i,h,w] + b[o]
// == GEMM: C[o, s] = W[o,:] . X[:, s],  s = n*784 + hw  (M=1024, N=25088, K=1024)
// fp32 in/out; compute in bf16 MFMA (threshold 3.72 ≈ 2% of max|ref| -> bf16 safe).

#define IN_C   1024
#define OUT_C  1024
#define HW     784          // 28*28, divisible by 16 -> aligned 16-chunks never cross batch
#define NB     32
#define NHW    (NB * HW)    // 25088 = 196 * 128 exactly
#define XSTR   (IN_C * HW)  // per-batch stride in x

#define BM 128
#define BN 128
#define BK 32
#define LDK 40              // padded k-stride in LDS (bf16 elems): 80B rows, 16B-aligned reads

typedef __bf16 bf16x8 __attribute__((ext_vector_type(8)));
typedef float  f32x4  __attribute__((ext_vector_type(4)));

__device__ __forceinline__ unsigned int bfbits(float f) {
    // round-half-up fp32 -> bf16, result in low 16 bits
    unsigned int u = __float_as_uint(f);
    return (u + 0x8000u) >> 16;
}
__device__ __forceinline__ unsigned int packpair(float k_even, float k_odd) {
    // little-endian: low half = lower LDS element (even k)
    return bfbits(k_even) | (bfbits(k_odd) << 16);
}

__global__ __launch_bounds__(256, 2)
void conv1x1_mfma(const float* __restrict__ X, const float* __restrict__ W,
                  const float* __restrict__ Bias, float* __restrict__ Out)
{
    __shared__ __align__(16) unsigned short lA[BM * LDK]; // [m][k]  10 KB
    __shared__ __align__(16) unsigned short lB[BN * LDK]; // [s][k]  10 KB

    const int t    = threadIdx.x;
    const int lane = t & 63;
    const int wid  = t >> 6;      // 4 waves: 2x2
    const int wm   = wid >> 1;
    const int wn   = wid & 1;

    const int s0 = blockIdx.x * BN;   // 196 tiles, exact
    const int bo = blockIdx.y * BM;   // 8 tiles, exact

    // ---- A staging map: t -> kchunk (float4) = t&7, row r0 = t>>3, rows r0+32*i
    const int kc4 = t & 7;
    const int r0  = t >> 3;
    const float* aptr = W + (bo + r0) * IN_C + kc4 * 4;

    // ---- B staging map: k-pair kp = t&15, s-chunk sc = t>>4 (8 consecutive s)
    const int kp = t & 15;
    const int sc = t >> 4;
    const int sglob = s0 + sc * 8;          // multiple of 8; 784%8==0 -> same batch
    const int nbat  = sglob / HW;
    const int hw0   = sglob % HW;
    const float* bptr = X + nbat * XSTR + hw0;

    f32x4 acc[4][4];
#pragma unroll
    for (int i = 0; i < 4; ++i)
#pragma unroll
        for (int j = 0; j < 4; ++j) acc[i][j] = 0.0f;

    for (int k0 = 0; k0 < IN_C; k0 += BK) {
        // global loads (issued before barrier -> overlap previous MFMA/barrier)
        f32x4 a[4];
#pragma unroll
        for (int i = 0; i < 4; ++i)
            a[i] = *(const f32x4*)(aptr + (i * 32) * IN_C + k0);
        const float* bp = bptr + (k0 + 2 * kp) * HW;
        f32x4 be0 = *(const f32x4*)(bp);
        f32x4 be1 = *(const f32x4*)(bp + 4);
        f32x4 bo0 = *(const f32x4*)(bp + HW);
        f32x4 bo1 = *(const f32x4*)(bp + HW + 4);

        __syncthreads();   // previous iteration's fragment reads done

        // A: row r0+32i gets 4 bf16 at k offset kc4*4
#pragma unroll
        for (int i = 0; i < 4; ++i) {
            unsigned int w0 = packpair(a[i][0], a[i][1]);
            unsigned int w1 = packpair(a[i][2], a[i][3]);
            unsigned long long p = ((unsigned long long)w1 << 32) | w0;
            *(unsigned long long*)&lA[(r0 + 32 * i) * LDK + kc4 * 4] = p;
        }
        // B transpose-at-write: s = sc*8 + c*4 + j gets k-pair (2kp, 2kp+1)
#pragma unroll
        for (int c = 0; c < 2; ++c) {
            const f32x4 ve = (c == 0) ? be0 : be1;
            const f32x4 vo = (c == 0) ? bo0 : bo1;
#pragma unroll
            for (int j = 0; j < 4; ++j) {
                *(unsigned int*)&lB[(sc * 8 + c * 4 + j) * LDK + 2 * kp] =
                    packpair(ve[j], vo[j]);
            }
        }
        __syncthreads();

        // fragments: both A and B read as [row][k], k-group (lane>>4)*8
        bf16x8 af[4], bfr[4];
        const int rsel = lane & 15;
        const int kg   = (lane >> 4) * 8;
#pragma unroll
        for (int fm = 0; fm < 4; ++fm)
            af[fm] = *(const bf16x8*)&lA[(wm * 64 + fm * 16 + rsel) * LDK + kg];
#pragma unroll
        for (int fn = 0; fn < 4; ++fn)
            bfr[fn] = *(const bf16x8*)&lB[(wn * 64 + fn * 16 + rsel) * LDK + kg];

#pragma unroll
        for (int fm = 0; fm < 4; ++fm)
#pragma unroll
            for (int fn = 0; fn < 4; ++fn)
                acc[fm][fn] = __builtin_amdgcn_mfma_f32_16x16x32_bf16(
                    af[fm], bfr[fn], acc[fm][fn], 0, 0, 0);
    }

    // ---- epilogue: C/D layout col=lane&15, row=(lane>>4)*4+r  [m89]
    const int ln15 = lane & 15;
    const int l4   = lane >> 4;

    int   nidx[4];
    int   hwb[4];
#pragma unroll
    for (int fn = 0; fn < 4; ++fn) {
        int sb = s0 + wn * 64 + fn * 16;   // multiple of 16; 784%16==0 -> same batch
        nidx[fn] = sb / HW;
        hwb[fn]  = sb % HW;
    }

#pragma unroll
    for (int fm = 0; fm < 4; ++fm) {
#pragma unroll
        for (int r = 0; r < 4; ++r) {
            const int o  = bo + wm * 64 + fm * 16 + l4 * 4 + r;
            const float bv = Bias[o];
#pragma unroll
            for (int fn = 0; fn < 4; ++fn) {
                Out[nidx[fn] * (OUT_C * HW) + o * HW + hwb[fn] + ln15] =
                    acc[fm][fn][r] + bv;
            }
        }
    }
}

extern "C" void kernel_launch(void* const* d_in, const int* in_sizes, int n_in,
                              void* d_out, int out_size, void* d_ws, size_t ws_size,
                              hipStream_t stream) {
    const float* x    = (const float*)d_in[0];  // [32,1024,28,28]
    const float* w    = (const float*)d_in[1];  // [1024,1024]
    const float* bias = (const float*)d_in[2];  // [1024,1]
    float* out = (float*)d_out;                 // [32,1024,28,28]

    dim3 grid(NHW / BN, OUT_C / BM);            // 196 x 8
    dim3 block(256);
    conv1x1_mfma<<<grid, block, 0, stream>>>(x, w, bias, out);
}

// Round 2
// 116.309 us; speedup vs baseline: 1.5238x; 1.5238x over previous
//
#include <hip/hip_runtime.h>

// SparseConv1x1 == GEMM: C[o,s] = W[o,:] . X[:,s] + b[o], s = n*784+hw
// M=1024, N=25088, K=1024, fp32 in/out, bf16 MFMA compute.
//
// Pipeline: (1) W -> bf16 swizzled, (2) x -> bf16 TRANSPOSED [s][k] swizzled,
// (3) m97-style 128x128 GEMM with global_load_lds(16B) staging.
// Swizzle: within each 128B chunk of a row, 16B-unit u is stored at u^(row&7);
// GEMM stages linearly (glds requirement) and reads with the same XOR -> ~2-way banks.

#define IN_C   1024
#define OUT_C  1024
#define HW     784
#define NB     32
#define NHW    (NB * HW)                 // 25088
#define XT_BYTES ((size_t)NHW * IN_C * 2)    // 51,380,224
#define WB_BYTES ((size_t)OUT_C * IN_C * 2)  // 2,097,152
#define WS_NEEDED (XT_BYTES + WB_BYTES)

typedef __bf16 bf16x8 __attribute__((ext_vector_type(8)));
typedef float  f32x4  __attribute__((ext_vector_type(4)));
typedef unsigned int u32x4 __attribute__((ext_vector_type(4)));

__device__ __forceinline__ unsigned int bfbits(float f) {
    unsigned int u = __float_as_uint(f);
    return (u + 0x8000u) >> 16;          // round-half-up fp32->bf16
}
__device__ __forceinline__ unsigned int packpair(float lo, float hi) {
    return bfbits(lo) | (bfbits(hi) << 16);
}
__device__ __forceinline__ void glds16(const void* g, void* l) {
    __builtin_amdgcn_global_load_lds(
        (const __attribute__((address_space(1))) void*)g,
        (__attribute__((address_space(3))) void*)l, 16, 0, 0);
}

// ---------- pre-pass 1: W [1024][1024] f32 -> Wb bf16, unit-swizzled ----------
__global__ void conv_w(const float* __restrict__ W, u32x4* __restrict__ Wb) {
    int gid = blockIdx.x * 256 + threadIdx.x;   // 131072 threads, 8 elems each
    int o = gid >> 7;                            // 128 16B-units per row
    int u = gid & 127;
    const float* p = W + o * 1024 + u * 8;
    f32x4 a = *(const f32x4*)p;
    f32x4 b = *(const f32x4*)(p + 4);
    u32x4 r;
    r.x = packpair(a[0], a[1]); r.y = packpair(a[2], a[3]);
    r.z = packpair(b[0], b[1]); r.w = packpair(b[2], b[3]);
    int us = u ^ (o & 7);                        // swizzle within 128B chunk
    Wb[o * 128 + us] = r;
}

// ---------- pre-pass 2: x [32][1024][784] f32 -> Xt [25088 s][1024 k] bf16 ----------
// thread (u = t&15, sr = t>>4): reads 8 k-strided floats for one s, writes one 16B unit.
__global__ void conv_x(const float* __restrict__ X, u32x4* __restrict__ Xt) {
    int st = blockIdx.x;                 // 49 tiles of 16 hw
    int kt = blockIdx.y;                 // 8 tiles of 128 k
    int n  = blockIdx.z;                 // 32 batches
    int t  = threadIdx.x;
    int u  = t & 15, sr = t >> 4;
    int hw = st * 16 + sr;
    int s  = n * HW + hw;
    const float* p = X + n * (IN_C * HW) + (kt * 128 + u * 8) * HW + hw;
    float v[8];
#pragma unroll
    for (int j = 0; j < 8; ++j) v[j] = p[j * HW];
    u32x4 r;
    r.x = packpair(v[0], v[1]); r.y = packpair(v[2], v[3]);
    r.z = packpair(v[4], v[5]); r.w = packpair(v[6], v[7]);
    int U  = kt * 16 + u;                // global 16B-unit index 0..127
    int Us = U ^ (s & 7);                // swizzle (affects low 3 bits only)
    Xt[(size_t)s * 128 + Us] = r;
}

// ---------- GEMM: m97 structure, 128x128 tile, BK=64, glds staging ----------
__global__ __launch_bounds__(256, 3)
void gemm_k(const char* __restrict__ Wb, const char* __restrict__ Xt,
            const float* __restrict__ Bias, float* __restrict__ Out)
{
    __shared__ __align__(16) char lA[128 * 128];  // [row][128B chunk], 16KB
    __shared__ __align__(16) char lB[128 * 128];

    const int t = threadIdx.x, lane = t & 63, wid = t >> 6;
    const int wm = wid >> 1, wn = wid & 1;

    // XCD swizzle: 8 o-blocks of one s-tile contiguous within an XCD
    const int bid = blockIdx.x;                   // 1568 = 8*196
    const int l   = (bid & 7) * 196 + (bid >> 3);
    const int bo  = (l & 7) * 128;
    const int s0  = (l >> 3) * 128;

    // staging: per glds, 8 lanes/row, 8 rows/instr, 4 instrs/wave per tile
    const char* ag = Wb + (size_t)(bo + wid * 32 + (lane >> 3)) * 2048 + (lane & 7) * 16;
    const char* bg = Xt + (size_t)(s0 + wid * 32 + (lane >> 3)) * 2048 + (lane & 7) * 16;
    char* la0 = &lA[(wid * 32) * 128];
    char* lb0 = &lB[(wid * 32) * 128];

    f32x4 acc[4][4];
#pragma unroll
    for (int i = 0; i < 4; ++i)
#pragma unroll
        for (int j = 0; j < 4; ++j) acc[i][j] = 0.0f;

    const int rsel = lane & 15, kg = lane >> 4;

    for (int c = 0; c < 16; ++c) {                // K chunks of 64
        const int cb = c * 128;
#pragma unroll
        for (int i = 0; i < 4; ++i) {
            glds16(ag + (size_t)i * (8 * 2048) + cb, la0 + i * (8 * 128));
            glds16(bg + (size_t)i * (8 * 2048) + cb, lb0 + i * (8 * 128));
        }
        __syncthreads();   // drains vmcnt -> tiles ready (and all waves staged)

#pragma unroll
        for (int kk = 0; kk < 2; ++kk) {
            bf16x8 af[4], bv[4];
#pragma unroll
            for (int fm = 0; fm < 4; ++fm) {
                const int row = wm * 64 + fm * 16 + rsel;
                const int u   = (kk * 4 + kg) ^ (row & 7);
                af[fm] = *(const bf16x8*)&lA[row * 128 + u * 16];
            }
#pragma unroll
            for (int fn = 0; fn < 4; ++fn) {
                const int row = wn * 64 + fn * 16 + rsel;
                const int u   = (kk * 4 + kg) ^ (row & 7);
                bv[fn] = *(const bf16x8*)&lB[row * 128 + u * 16];
            }
#pragma unroll
            for (int fm = 0; fm < 4; ++fm)
#pragma unroll
                for (int fn = 0; fn < 4; ++fn)
                    acc[fm][fn] = __builtin_amdgcn_mfma_f32_16x16x32_bf16(
                        af[fm], bv[fn], acc[fm][fn], 0, 0, 0);
        }
        __syncthreads();   // all reads done before next stage overwrites
    }

    // epilogue: C/D layout col=lane&15, row=(lane>>4)*4+r
    const int ln15 = lane & 15, l4 = lane >> 4;
    int nidx[4], hwb[4];
#pragma unroll
    for (int fn = 0; fn < 4; ++fn) {
        int sb = s0 + wn * 64 + fn * 16;          // 784%16==0 -> same batch per 16-run
        nidx[fn] = sb / HW;
        hwb[fn]  = sb % HW;
    }
#pragma unroll
    for (int fm = 0; fm < 4; ++fm) {
#pragma unroll
        for (int r = 0; r < 4; ++r) {
            const int o = bo + wm * 64 + fm * 16 + l4 * 4 + r;
            const float bvs = Bias[o];
#pragma unroll
            for (int fn = 0; fn < 4; ++fn)
                Out[(size_t)nidx[fn] * (OUT_C * HW) + o * HW + hwb[fn] + ln15] =
                    acc[fm][fn][r] + bvs;
        }
    }
}

// ---------- fallback (round-1 kernel, used if ws too small) ----------
#define BM 128
#define BN 128
#define LDK 40
__global__ __launch_bounds__(256, 2)
void conv1x1_fallback(const float* __restrict__ X, const float* __restrict__ W,
                      const float* __restrict__ Bias, float* __restrict__ Out)
{
    __shared__ __align__(16) unsigned short lA[BM * LDK];
    __shared__ __align__(16) unsigned short lB[BN * LDK];
    const int t = threadIdx.x, lane = t & 63, wid = t >> 6;
    const int wm = wid >> 1, wn = wid & 1;
    const int s0 = blockIdx.x * BN, bo = blockIdx.y * BM;
    const int kc4 = t & 7, r0 = t >> 3;
    const float* aptr = W + (bo + r0) * IN_C + kc4 * 4;
    const int kp = t & 15, sc = t >> 4;
    const int sglob = s0 + sc * 8;
    const int nbat = sglob / HW, hw0 = sglob % HW;
    const float* bptr = X + nbat * (IN_C * HW) + hw0;
    f32x4 acc[4][4];
#pragma unroll
    for (int i = 0; i < 4; ++i)
#pragma unroll
        for (int j = 0; j < 4; ++j) acc[i][j] = 0.0f;
    for (int k0 = 0; k0 < IN_C; k0 += 32) {
        f32x4 a[4];
#pragma unroll
        for (int i = 0; i < 4; ++i) a[i] = *(const f32x4*)(aptr + (i * 32) * IN_C + k0);
        const float* bp = bptr + (k0 + 2 * kp) * HW;
        f32x4 be0 = *(const f32x4*)(bp), be1 = *(const f32x4*)(bp + 4);
        f32x4 bo0 = *(const f32x4*)(bp + HW), bo1 = *(const f32x4*)(bp + HW + 4);
        __syncthreads();
#pragma unroll
        for (int i = 0; i < 4; ++i) {
            unsigned int w0 = packpair(a[i][0], a[i][1]);
            unsigned int w1 = packpair(a[i][2], a[i][3]);
            unsigned long long pq = ((unsigned long long)w1 << 32) | w0;
            *(unsigned long long*)&lA[(r0 + 32 * i) * LDK + kc4 * 4] = pq;
        }
#pragma unroll
        for (int c2 = 0; c2 < 2; ++c2) {
            const f32x4 ve = (c2 == 0) ? be0 : be1;
            const f32x4 vo = (c2 == 0) ? bo0 : bo1;
#pragma unroll
            for (int j = 0; j < 4; ++j)
                *(unsigned int*)&lB[(sc * 8 + c2 * 4 + j) * LDK + 2 * kp] = packpair(ve[j], vo[j]);
        }
        __syncthreads();
        bf16x8 af[4], bfr[4];
        const int rsel = lane & 15, kgp = (lane >> 4) * 8;
#pragma unroll
        for (int fm = 0; fm < 4; ++fm)
            af[fm] = *(const bf16x8*)&lA[(wm * 64 + fm * 16 + rsel) * LDK + kgp];
#pragma unroll
        for (int fn = 0; fn < 4; ++fn)
            bfr[fn] = *(const bf16x8*)&lB[(wn * 64 + fn * 16 + rsel) * LDK + kgp];
#pragma unroll
        for (int fm = 0; fm < 4; ++fm)
#pragma unroll
            for (int fn = 0; fn < 4; ++fn)
                acc[fm][fn] = __builtin_amdgcn_mfma_f32_16x16x32_bf16(af[fm], bfr[fn], acc[fm][fn], 0, 0, 0);
    }
    const int ln15 = lane & 15, l4 = lane >> 4;
    int nidx[4], hwb[4];
#pragma unroll
    for (int fn = 0; fn < 4; ++fn) {
        int sb = s0 + wn * 64 + fn * 16;
        nidx[fn] = sb / HW; hwb[fn] = sb % HW;
    }
#pragma unroll
    for (int fm = 0; fm < 4; ++fm)
#pragma unroll
        for (int r = 0; r < 4; ++r) {
            const int o = bo + wm * 64 + fm * 16 + l4 * 4 + r;
            const float bvs = Bias[o];
#pragma unroll
            for (int fn = 0; fn < 4; ++fn)
                Out[(size_t)nidx[fn] * (OUT_C * HW) + o * HW + hwb[fn] + ln15] = acc[fm][fn][r] + bvs;
        }
}

extern "C" void kernel_launch(void* const* d_in, const int* in_sizes, int n_in,
                              void* d_out, int out_size, void* d_ws, size_t ws_size,
                              hipStream_t stream) {
    const float* x    = (const float*)d_in[0];
    const float* w    = (const float*)d_in[1];
    const float* bias = (const float*)d_in[2];
    float* out = (float*)d_out;

    if (ws_size >= WS_NEEDED) {
        char* xt = (char*)d_ws;
        char* wb = (char*)d_ws + XT_BYTES;
        conv_w<<<512, 256, 0, stream>>>(w, (u32x4*)wb);
        conv_x<<<dim3(49, 8, 32), 256, 0, stream>>>(x, (u32x4*)xt);
        gemm_k<<<1568, 256, 0, stream>>>(wb, xt, bias, out);
    } else {
        dim3 grid(NHW / BN, OUT_C / BM);
        conv1x1_fallback<<<grid, 256, 0, stream>>>(x, w, bias, out);
    }
}

// Round 3
// 109.521 us; speedup vs baseline: 1.6183x; 1.0620x over previous
//
#include <hip/hip_runtime.h>

// SparseConv1x1 == GEMM: C[o,s] = W[o,:] . X[:,s] + b[o], s = n*784+hw
// M=1024, N=25088, K=1024, fp32 in/out, bf16 MFMA compute.
// Round 3: 256x256 8-phase-style GEMM (T2+T3+T4+T5) + LDS-transpose conv_x.

#define IN_C   1024
#define OUT_C  1024
#define HW     784
#define NB     32
#define NHW    (NB * HW)                     // 25088
#define XT_BYTES ((size_t)NHW * IN_C * 2)    // 51,380,224
#define WB_BYTES ((size_t)OUT_C * IN_C * 2)  // 2,097,152
#define WS_NEEDED (XT_BYTES + WB_BYTES)
#define NKT 16                               // K tiles of 64

typedef __bf16 bf16x8 __attribute__((ext_vector_type(8)));
typedef float  f32x4  __attribute__((ext_vector_type(4)));
typedef unsigned int u32x4 __attribute__((ext_vector_type(4)));

__device__ __forceinline__ unsigned int bfbits(float f) {
    unsigned int u = __float_as_uint(f);
    return (u + 0x8000u) >> 16;              // round-half-up fp32->bf16
}
__device__ __forceinline__ unsigned int packpair(float lo, float hi) {
    return bfbits(lo) | (bfbits(hi) << 16);
}
__device__ __forceinline__ void glds16(const void* g, void* l) {
    __builtin_amdgcn_global_load_lds(
        (const __attribute__((address_space(1))) void*)g,
        (__attribute__((address_space(3))) void*)l, 16, 0, 0);
}

// ---------- pre-pass 1: W [1024][1024] f32 -> Wb bf16, unit-swizzled ----------
__global__ void conv_w(const float* __restrict__ W, u32x4* __restrict__ Wb) {
    int gid = blockIdx.x * 256 + threadIdx.x;
    int o = gid >> 7;
    int u = gid & 127;
    const float* p = W + o * 1024 + u * 8;
    f32x4 a = *(const f32x4*)p;
    f32x4 b = *(const f32x4*)(p + 4);
    u32x4 r;
    r.x = packpair(a[0], a[1]); r.y = packpair(a[2], a[3]);
    r.z = packpair(b[0], b[1]); r.w = packpair(b[2], b[3]);
    int us = u ^ (o & 7);
    Wb[o * 128 + us] = r;
}

// ---------- pre-pass 2: x -> Xt [s][k] bf16 swizzled, LDS transpose ----------
// block: 16 hw x 1024 k. Coalesced f32x4 reads (64B segs), coalesced 16B-unit writes.
#define XPAD 1040
__global__ __launch_bounds__(256)
void conv_x2(const float* __restrict__ X, u32x4* __restrict__ Xt) {
    __shared__ unsigned short T[16 * XPAD];   // 33,280 B
    const int st = blockIdx.x;                // 49 hw-tiles of 16
    const int n  = blockIdx.y;                // 32 batches
    const int t  = threadIdx.x;

    // load+convert: 16 passes x (64 k-rows x 16 hw)
    const int hw4 = t & 3, kr = t >> 2;       // kr 0..63
    const float* base = X + ((size_t)n * IN_C + kr) * HW + st * 16 + hw4 * 4;
#pragma unroll 4
    for (int p = 0; p < 16; ++p) {
        f32x4 v = *(const f32x4*)(base + (size_t)p * 64 * HW);
        const int k = p * 64 + kr;
#pragma unroll
        for (int j = 0; j < 4; ++j)
            T[(hw4 * 4 + j) * XPAD + k] = (unsigned short)bfbits(v[j]);
    }
    __syncthreads();

    // store: 8 swizzled 16B units per thread, coalesced per 16-lane group
    const int hw = t >> 4, u0 = t & 15;
    const int s = n * HW + st * 16 + hw;
    u32x4* dst = Xt + (size_t)s * 128;
    const unsigned short* src = &T[hw * XPAD];
#pragma unroll
    for (int j = 0; j < 8; ++j) {
        const int u = u0 + 16 * j;
        u32x4 v = *(const u32x4*)(src + u * 8);
        dst[u ^ (s & 7)] = v;
    }
}

// ---------- GEMM: 256x256 tile, BK=64, 8 waves, 4-phase/K-tile counted-vmcnt ----
__global__ __launch_bounds__(512, 2)
void gemm8(const char* __restrict__ Wb, const char* __restrict__ Xt,
           const float* __restrict__ Bias, float* __restrict__ Out)
{
    __shared__ __align__(16) char sm[131072];      // lA[2][256][128B] | lB[2][256][128B]
    char* lA = sm;
    char* lB = sm + 65536;

    const int t = threadIdx.x, lane = t & 63, w = t >> 6;
    const int wm = w >> 2;        // 0..1  (M half)
    const int wn = w & 3;         // 0..3  (N quarter)

    // XCD swizzle: 392 = 8*49; same-XCD blocks share B-tiles (4 m-tiles per ntile)
    const int bid = blockIdx.x;
    const int l   = (bid & 7) * 49 + (bid >> 3);
    const int bo  = (l & 3) * 256;
    const int s0  = (l >> 2) * 256;

    const int srow  = lane >> 3;          // row within 8-row chunk
    const int sunit = (lane & 7) * 16;    // byte within 128B row

    // stage one A-half (128 rows x 64 k = 16KB): 2 glds/thread
    auto stA = [&](int buf, int half, int kt) {
#pragma unroll
        for (int j = 0; j < 2; ++j) {
            const int r = half * 128 + w * 16 + j * 8;      // LDS chunk base row
            const char* src = Wb + (size_t)(bo + r + srow) * 2048 + kt * 128 + sunit;
            glds16(src, lA + buf * 32768 + r * 128);
        }
    };
    auto stB = [&](int buf, int half, int kt) {
#pragma unroll
        for (int j = 0; j < 2; ++j) {
            const int r = half * 128 + w * 16 + j * 8;
            const char* src = Xt + (size_t)(s0 + r + srow) * 2048 + kt * 128 + sunit;
            glds16(src, lB + buf * 32768 + r * 128);
        }
    };

    // prologue: T0 fully + T1's B halves; guarantee T0 landed (12 issued, wait<=4)
    stA(0, 0, 0); stA(0, 1, 0); stB(0, 0, 0); stB(0, 1, 0);
    stB(1, 0, 1); stB(1, 1, 1);
    asm volatile("s_waitcnt vmcnt(4)" ::: "memory");
    __builtin_amdgcn_s_barrier();

    f32x4 acc[8][4];
#pragma unroll
    for (int i = 0; i < 8; ++i)
#pragma unroll
        for (int j = 0; j < 4; ++j) acc[i][j] = 0.0f;

    const int rsel = lane & 15, kg = lane >> 4;

    for (int kt = 0; kt < NKT; ++kt) {
        const int buf = kt & 1;
        const char* Ab = lA + buf * 32768;
        const char* Bb = lB + buf * 32768;
        bf16x8 bfr[2][4];                       // [kk][fn] — whole K-tile's B frags

#pragma unroll
        for (int quad = 0; quad < 4; ++quad) {
            // ---- ds-read register subtile
            if (quad == 0) {
#pragma unroll
                for (int kk = 0; kk < 2; ++kk)
#pragma unroll
                    for (int fn = 0; fn < 4; ++fn) {
                        const int row = wn * 64 + fn * 16 + rsel;
                        const int u   = (kk * 4 + kg) ^ (row & 7);
                        bfr[kk][fn] = *(const bf16x8*)(Bb + row * 128 + u * 16);
                    }
            }
            bf16x8 af[2][2];                    // [fm][kk]
#pragma unroll
            for (int fm = 0; fm < 2; ++fm)
#pragma unroll
                for (int kk = 0; kk < 2; ++kk) {
                    const int row = wm * 128 + quad * 32 + fm * 16 + rsel;
                    const int u   = (kk * 4 + kg) ^ (row & 7);
                    af[fm][kk] = *(const bf16x8*)(Ab + row * 128 + u * 16);
                }

            // ---- stage 1 half-tile (A of kt+1 -> buf^1; B of kt+2 -> buf)
            if      (quad == 0) { if (kt + 1 < NKT) stA(buf ^ 1, 0, kt + 1); }
            else if (quad == 1) { if (kt + 1 < NKT) stA(buf ^ 1, 1, kt + 1); }
            else if (quad == 2) { if (kt + 2 < NKT) stB(buf,     0, kt + 2); }
            else                { if (kt + 2 < NKT) stB(buf,     1, kt + 2); }

            __builtin_amdgcn_s_barrier();

            // ---- 16 MFMA (one m-quadrant x full N x BK=64)
            __builtin_amdgcn_s_setprio(1);
#pragma unroll
            for (int fm = 0; fm < 2; ++fm)
#pragma unroll
                for (int fn = 0; fn < 4; ++fn)
#pragma unroll
                    for (int kk = 0; kk < 2; ++kk)
                        acc[quad * 2 + fm][fn] = __builtin_amdgcn_mfma_f32_16x16x32_bf16(
                            af[fm][kk], bfr[kk][fn], acc[quad * 2 + fm][fn], 0, 0, 0);
            __builtin_amdgcn_s_setprio(0);

            if (quad < 3) __builtin_amdgcn_s_barrier();
        }

        // ---- iteration end: counted vmcnt (all but last 2 half-tiles landed)
        if (kt < NKT - 2) asm volatile("s_waitcnt vmcnt(4)" ::: "memory");
        else              asm volatile("s_waitcnt vmcnt(0)" ::: "memory");
        __builtin_amdgcn_s_barrier();
    }

    // ---- epilogue: C/D layout col=lane&15, row=(lane>>4)*4+r; add bias
    const int ln15 = lane & 15, l4 = lane >> 4;
    int nidx[4], hwb[4];
#pragma unroll
    for (int fn = 0; fn < 4; ++fn) {
        const int sb = s0 + wn * 64 + fn * 16;   // mult of 16; 784%16==0
        nidx[fn] = sb / HW;
        hwb[fn]  = sb % HW;
    }
#pragma unroll
    for (int fm = 0; fm < 8; ++fm) {
#pragma unroll
        for (int r = 0; r < 4; ++r) {
            const int o = bo + wm * 128 + fm * 16 + l4 * 4 + r;
            const float bvs = Bias[o];
#pragma unroll
            for (int fn = 0; fn < 4; ++fn)
                Out[(size_t)nidx[fn] * (OUT_C * HW) + o * HW + hwb[fn] + ln15] =
                    acc[fm][fn][r] + bvs;
        }
    }
}

// ---------- fallback (round-1 kernel, used only if ws too small) ----------
#define BM 128
#define BN 128
#define LDK 40
__global__ __launch_bounds__(256, 2)
void conv1x1_fallback(const float* __restrict__ X, const float* __restrict__ W,
                      const float* __restrict__ Bias, float* __restrict__ Out)
{
    __shared__ __align__(16) unsigned short lA[BM * LDK];
    __shared__ __align__(16) unsigned short lB[BN * LDK];
    const int t = threadIdx.x, lane = t & 63, wid = t >> 6;
    const int wm = wid >> 1, wn = wid & 1;
    const int s0 = blockIdx.x * BN, bo = blockIdx.y * BM;
    const int kc4 = t & 7, r0 = t >> 3;
    const float* aptr = W + (bo + r0) * IN_C + kc4 * 4;
    const int kp = t & 15, sc = t >> 4;
    const int sglob = s0 + sc * 8;
    const int nbat = sglob / HW, hw0 = sglob % HW;
    const float* bptr = X + nbat * (IN_C * HW) + hw0;
    f32x4 acc[4][4];
#pragma unroll
    for (int i = 0; i < 4; ++i)
#pragma unroll
        for (int j = 0; j < 4; ++j) acc[i][j] = 0.0f;
    for (int k0 = 0; k0 < IN_C; k0 += 32) {
        f32x4 a[4];
#pragma unroll
        for (int i = 0; i < 4; ++i) a[i] = *(const f32x4*)(aptr + (i * 32) * IN_C + k0);
        const float* bp = bptr + (k0 + 2 * kp) * HW;
        f32x4 be0 = *(const f32x4*)(bp), be1 = *(const f32x4*)(bp + 4);
        f32x4 bo0 = *(const f32x4*)(bp + HW), bo1 = *(const f32x4*)(bp + HW + 4);
        __syncthreads();
#pragma unroll
        for (int i = 0; i < 4; ++i) {
            unsigned int w0 = packpair(a[i][0], a[i][1]);
            unsigned int w1 = packpair(a[i][2], a[i][3]);
            unsigned long long pq = ((unsigned long long)w1 << 32) | w0;
            *(unsigned long long*)&lA[(r0 + 32 * i) * LDK + kc4 * 4] = pq;
        }
#pragma unroll
        for (int c2 = 0; c2 < 2; ++c2) {
            const f32x4 ve = (c2 == 0) ? be0 : be1;
            const f32x4 vo = (c2 == 0) ? bo0 : bo1;
#pragma unroll
            for (int j = 0; j < 4; ++j)
                *(unsigned int*)&lB[(sc * 8 + c2 * 4 + j) * LDK + 2 * kp] = packpair(ve[j], vo[j]);
        }
        __syncthreads();
        bf16x8 af[4], bfr[4];
        const int rsel = lane & 15, kgp = (lane >> 4) * 8;
#pragma unroll
        for (int fm = 0; fm < 4; ++fm)
            af[fm] = *(const bf16x8*)&lA[(wm * 64 + fm * 16 + rsel) * LDK + kgp];
#pragma unroll
        for (int fn = 0; fn < 4; ++fn)
            bfr[fn] = *(const bf16x8*)&lB[(wn * 64 + fn * 16 + rsel) * LDK + kgp];
#pragma unroll
        for (int fm = 0; fm < 4; ++fm)
#pragma unroll
            for (int fn = 0; fn < 4; ++fn)
                acc[fm][fn] = __builtin_amdgcn_mfma_f32_16x16x32_bf16(af[fm], bfr[fn], acc[fm][fn], 0, 0, 0);
    }
    const int ln15 = lane & 15, l4 = lane >> 4;
    int nidx[4], hwb[4];
#pragma unroll
    for (int fn = 0; fn < 4; ++fn) {
        int sb = s0 + wn * 64 + fn * 16;
        nidx[fn] = sb / HW; hwb[fn] = sb % HW;
    }
#pragma unroll
    for (int fm = 0; fm < 4; ++fm)
#pragma unroll
        for (int r = 0; r < 4; ++r) {
            const int o = bo + wm * 64 + fm * 16 + l4 * 4 + r;
            const float bvs = Bias[o];
#pragma unroll
            for (int fn = 0; fn < 4; ++fn)
                Out[(size_t)nidx[fn] * (OUT_C * HW) + o * HW + hwb[fn] + ln15] = acc[fm][fn][r] + bvs;
        }
}

extern "C" void kernel_launch(void* const* d_in, const int* in_sizes, int n_in,
                              void* d_out, int out_size, void* d_ws, size_t ws_size,
                              hipStream_t stream) {
    const float* x    = (const float*)d_in[0];
    const float* w    = (const float*)d_in[1];
    const float* bias = (const float*)d_in[2];
    float* out = (float*)d_out;

    if (ws_size >= WS_NEEDED) {
        char* xt = (char*)d_ws;
        char* wb = (char*)d_ws + XT_BYTES;
        conv_w<<<512, 256, 0, stream>>>(w, (u32x4*)wb);
        conv_x2<<<dim3(49, 32), 256, 0, stream>>>(x, (u32x4*)xt);
        gemm8<<<392, 512, 0, stream>>>(wb, xt, bias, out);
    } else {
        dim3 grid(NHW / BN, OUT_C / BM);
        conv1x1_fallback<<<grid, 256, 0, stream>>>(x, w, bias, out);
    }
}

// Round 4
// 104.802 us; speedup vs baseline: 1.6912x; 1.0450x over previous
//
#include <hip/hip_runtime.h>

// SparseConv1x1 == GEMM: C[o,s] = W[o,:] . X[:,s] + b[o], s = n*784+hw
// M=1024, N=25088, K=1024, fp32 in/out, bf16 MFMA compute.
// Round 4: fix gemm8 dependent-MFMA stall (kk-outer ordering); merge prepasses.

#define IN_C   1024
#define OUT_C  1024
#define HW     784
#define NB     32
#define NHW    (NB * HW)                     // 25088
#define XT_BYTES ((size_t)NHW * IN_C * 2)    // 51,380,224
#define WB_BYTES ((size_t)OUT_C * IN_C * 2)  // 2,097,152
#define WS_NEEDED (XT_BYTES + WB_BYTES)
#define NKT 16                               // K tiles of 64

typedef __bf16 bf16x8 __attribute__((ext_vector_type(8)));
typedef float  f32x4  __attribute__((ext_vector_type(4)));
typedef unsigned int u32x4 __attribute__((ext_vector_type(4)));

__device__ __forceinline__ unsigned int bfbits(float f) {
    unsigned int u = __float_as_uint(f);
    return (u + 0x8000u) >> 16;              // round-half-up fp32->bf16
}
__device__ __forceinline__ unsigned int packpair(float lo, float hi) {
    return bfbits(lo) | (bfbits(hi) << 16);
}
__device__ __forceinline__ void glds16(const void* g, void* l) {
    __builtin_amdgcn_global_load_lds(
        (const __attribute__((address_space(1))) void*)g,
        (__attribute__((address_space(3))) void*)l, 16, 0, 0);
}

// ---------- combined pre-pass: blocks [0,512) convert W, [512,2080) transpose x ----
#define XPAD 1040
__global__ __launch_bounds__(256)
void conv_pre(const float* __restrict__ X, const float* __restrict__ W,
              u32x4* __restrict__ Xt, u32x4* __restrict__ Wb)
{
    __shared__ unsigned short T[16 * XPAD];   // 33,280 B (x-path only)
    const int t = threadIdx.x;

    if (blockIdx.x < 512) {
        // W [1024][1024] f32 -> Wb bf16, unit-swizzled
        int gid = blockIdx.x * 256 + t;
        int o = gid >> 7;
        int u = gid & 127;
        const float* p = W + o * 1024 + u * 8;
        f32x4 a = *(const f32x4*)p;
        f32x4 b = *(const f32x4*)(p + 4);
        u32x4 r;
        r.x = packpair(a[0], a[1]); r.y = packpair(a[2], a[3]);
        r.z = packpair(b[0], b[1]); r.w = packpair(b[2], b[3]);
        Wb[o * 128 + (u ^ (o & 7))] = r;
        return;
    }

    // x [32][1024][784] f32 -> Xt [25088 s][1024 k] bf16 swizzled (LDS transpose)
    const int b  = blockIdx.x - 512;          // 1568 = 49 * 32
    const int st = b % 49;
    const int n  = b / 49;

    const int hw4 = t & 3, kr = t >> 2;       // kr 0..63
    const float* base = X + ((size_t)n * IN_C + kr) * HW + st * 16 + hw4 * 4;
#pragma unroll 4
    for (int p = 0; p < 16; ++p) {
        f32x4 v = *(const f32x4*)(base + (size_t)p * 64 * HW);
        const int k = p * 64 + kr;
#pragma unroll
        for (int j = 0; j < 4; ++j)
            T[(hw4 * 4 + j) * XPAD + k] = (unsigned short)bfbits(v[j]);
    }
    __syncthreads();

    const int hw = t >> 4, u0 = t & 15;
    const int s = n * HW + st * 16 + hw;
    u32x4* dst = Xt + (size_t)s * 128;
    const unsigned short* src = &T[hw * XPAD];
#pragma unroll
    for (int j = 0; j < 8; ++j) {
        const int u = u0 + 16 * j;
        u32x4 v = *(const u32x4*)(src + u * 8);
        dst[u ^ (s & 7)] = v;
    }
}

// ---------- GEMM: 256x256 tile, BK=64, 8 waves, 4-phase/K-tile counted-vmcnt ----
__global__ __launch_bounds__(512, 2)
void gemm8(const char* __restrict__ Wb, const char* __restrict__ Xt,
           const float* __restrict__ Bias, float* __restrict__ Out)
{
    __shared__ __align__(16) char sm[131072];      // lA[2][256][128B] | lB[2][256][128B]
    char* lA = sm;
    char* lB = sm + 65536;

    const int t = threadIdx.x, lane = t & 63, w = t >> 6;
    const int wm = w >> 2;        // 0..1  (M half)
    const int wn = w & 3;         // 0..3  (N quarter)

    // XCD swizzle: 392 = 8*49; same-XCD blocks share B-tiles (4 m-tiles per ntile)
    const int bid = blockIdx.x;
    const int l   = (bid & 7) * 49 + (bid >> 3);
    const int bo  = (l & 3) * 256;
    const int s0  = (l >> 2) * 256;

    const int srow  = lane >> 3;          // row within 8-row chunk
    const int sunit = (lane & 7) * 16;    // byte within 128B row

    auto stA = [&](int buf, int half, int kt) {
#pragma unroll
        for (int j = 0; j < 2; ++j) {
            const int r = half * 128 + w * 16 + j * 8;
            const char* src = Wb + (size_t)(bo + r + srow) * 2048 + kt * 128 + sunit;
            glds16(src, lA + buf * 32768 + r * 128);
        }
    };
    auto stB = [&](int buf, int half, int kt) {
#pragma unroll
        for (int j = 0; j < 2; ++j) {
            const int r = half * 128 + w * 16 + j * 8;
            const char* src = Xt + (size_t)(s0 + r + srow) * 2048 + kt * 128 + sunit;
            glds16(src, lB + buf * 32768 + r * 128);
        }
    };

    // prologue: T0 fully + T1's B halves; vmcnt(4) -> T0 landed, B(T1) in flight
    stA(0, 0, 0); stA(0, 1, 0); stB(0, 0, 0); stB(0, 1, 0);
    stB(1, 0, 1); stB(1, 1, 1);
    asm volatile("s_waitcnt vmcnt(4)" ::: "memory");
    __builtin_amdgcn_s_barrier();

    f32x4 acc[8][4];
#pragma unroll
    for (int i = 0; i < 8; ++i)
#pragma unroll
        for (int j = 0; j < 4; ++j) acc[i][j] = 0.0f;

    const int rsel = lane & 15, kg = lane >> 4;

    for (int kt = 0; kt < NKT; ++kt) {
        const int buf = kt & 1;
        const char* Ab = lA + buf * 32768;
        const char* Bb = lB + buf * 32768;
        bf16x8 bfr[2][4];                       // [kk][fn] — whole K-tile's B frags

#pragma unroll
        for (int quad = 0; quad < 4; ++quad) {
            // ---- ds-read register subtile
            if (quad == 0) {
#pragma unroll
                for (int kk = 0; kk < 2; ++kk)
#pragma unroll
                    for (int fn = 0; fn < 4; ++fn) {
                        const int row = wn * 64 + fn * 16 + rsel;
                        const int u   = (kk * 4 + kg) ^ (row & 7);
                        bfr[kk][fn] = *(const bf16x8*)(Bb + row * 128 + u * 16);
                    }
            }
            bf16x8 af[2][2];                    // [fm][kk]
#pragma unroll
            for (int fm = 0; fm < 2; ++fm)
#pragma unroll
                for (int kk = 0; kk < 2; ++kk) {
                    const int row = wm * 128 + quad * 32 + fm * 16 + rsel;
                    const int u   = (kk * 4 + kg) ^ (row & 7);
                    af[fm][kk] = *(const bf16x8*)(Ab + row * 128 + u * 16);
                }

            // ---- stage 1 half-tile (A of kt+1 -> buf^1; B of kt+2 -> buf)
            if      (quad == 0) { if (kt + 1 < NKT) stA(buf ^ 1, 0, kt + 1); }
            else if (quad == 1) { if (kt + 1 < NKT) stA(buf ^ 1, 1, kt + 1); }
            else if (quad == 2) { if (kt + 2 < NKT) stB(buf,     0, kt + 2); }
            else                { if (kt + 2 < NKT) stB(buf,     1, kt + 2); }

            __builtin_amdgcn_s_barrier();

            // ---- 16 MFMA, kk OUTER: dependents (same acc) are 8 instrs apart
            __builtin_amdgcn_s_setprio(1);
#pragma unroll
            for (int kk = 0; kk < 2; ++kk)
#pragma unroll
                for (int fm = 0; fm < 2; ++fm)
#pragma unroll
                    for (int fn = 0; fn < 4; ++fn)
                        acc[quad * 2 + fm][fn] = __builtin_amdgcn_mfma_f32_16x16x32_bf16(
                            af[fm][kk], bfr[kk][fn], acc[quad * 2 + fm][fn], 0, 0, 0);
            __builtin_amdgcn_s_setprio(0);

            if (quad < 3) __builtin_amdgcn_s_barrier();
        }

        // ---- iteration end: counted vmcnt (A(kt+1),B(kt+1) landed; B(kt+2) in flight)
        if (kt < NKT - 2) asm volatile("s_waitcnt vmcnt(4)" ::: "memory");
        else              asm volatile("s_waitcnt vmcnt(0)" ::: "memory");
        __builtin_amdgcn_s_barrier();
    }

    // ---- epilogue: C/D layout col=lane&15, row=(lane>>4)*4+r; add bias
    const int ln15 = lane & 15, l4 = lane >> 4;
    int nidx[4], hwb[4];
#pragma unroll
    for (int fn = 0; fn < 4; ++fn) {
        const int sb = s0 + wn * 64 + fn * 16;   // mult of 16; 784%16==0
        nidx[fn] = sb / HW;
        hwb[fn]  = sb % HW;
    }
#pragma unroll
    for (int fm = 0; fm < 8; ++fm) {
#pragma unroll
        for (int r = 0; r < 4; ++r) {
            const int o = bo + wm * 128 + fm * 16 + l4 * 4 + r;
            const float bvs = Bias[o];
#pragma unroll
            for (int fn = 0; fn < 4; ++fn)
                Out[(size_t)nidx[fn] * (OUT_C * HW) + o * HW + hwb[fn] + ln15] =
                    acc[fm][fn][r] + bvs;
        }
    }
}

// ---------- fallback (round-1 kernel, used only if ws too small) ----------
#define BM 128
#define BN 128
#define LDK 40
__global__ __launch_bounds__(256, 2)
void conv1x1_fallback(const float* __restrict__ X, const float* __restrict__ W,
                      const float* __restrict__ Bias, float* __restrict__ Out)
{
    __shared__ __align__(16) unsigned short lA[BM * LDK];
    __shared__ __align__(16) unsigned short lB[BN * LDK];
    const int t = threadIdx.x, lane = t & 63, wid = t >> 6;
    const int wm = wid >> 1, wn = wid & 1;
    const int s0 = blockIdx.x * BN, bo = blockIdx.y * BM;
    const int kc4 = t & 7, r0 = t >> 3;
    const float* aptr = W + (bo + r0) * IN_C + kc4 * 4;
    const int kp = t & 15, sc = t >> 4;
    const int sglob = s0 + sc * 8;
    const int nbat = sglob / HW, hw0 = sglob % HW;
    const float* bptr = X + nbat * (IN_C * HW) + hw0;
    f32x4 acc[4][4];
#pragma unroll
    for (int i = 0; i < 4; ++i)
#pragma unroll
        for (int j = 0; j < 4; ++j) acc[i][j] = 0.0f;
    for (int k0 = 0; k0 < IN_C; k0 += 32) {
        f32x4 a[4];
#pragma unroll
        for (int i = 0; i < 4; ++i) a[i] = *(const f32x4*)(aptr + (i * 32) * IN_C + k0);
        const float* bp = bptr + (k0 + 2 * kp) * HW;
        f32x4 be0 = *(const f32x4*)(bp), be1 = *(const f32x4*)(bp + 4);
        f32x4 bo0 = *(const f32x4*)(bp + HW), bo1 = *(const f32x4*)(bp + HW + 4);
        __syncthreads();
#pragma unroll
        for (int i = 0; i < 4; ++i) {
            unsigned int w0 = packpair(a[i][0], a[i][1]);
            unsigned int w1 = packpair(a[i][2], a[i][3]);
            unsigned long long pq = ((unsigned long long)w1 << 32) | w0;
            *(unsigned long long*)&lA[(r0 + 32 * i) * LDK + kc4 * 4] = pq;
        }
#pragma unroll
        for (int c2 = 0; c2 < 2; ++c2) {
            const f32x4 ve = (c2 == 0) ? be0 : be1;
            const f32x4 vo = (c2 == 0) ? bo0 : bo1;
#pragma unroll
            for (int j = 0; j < 4; ++j)
                *(unsigned int*)&lB[(sc * 8 + c2 * 4 + j) * LDK + 2 * kp] = packpair(ve[j], vo[j]);
        }
        __syncthreads();
        bf16x8 af[4], bfr[4];
        const int rsel = lane & 15, kgp = (lane >> 4) * 8;
#pragma unroll
        for (int fm = 0; fm < 4; ++fm)
            af[fm] = *(const bf16x8*)&lA[(wm * 64 + fm * 16 + rsel) * LDK + kgp];
#pragma unroll
        for (int fn = 0; fn < 4; ++fn)
            bfr[fn] = *(const bf16x8*)&lB[(wn * 64 + fn * 16 + rsel) * LDK + kgp];
#pragma unroll
        for (int fm = 0; fm < 4; ++fm)
#pragma unroll
            for (int fn = 0; fn < 4; ++fn)
                acc[fm][fn] = __builtin_amdgcn_mfma_f32_16x16x32_bf16(af[fm], bfr[fn], acc[fm][fn], 0, 0, 0);
    }
    const int ln15 = lane & 15, l4 = lane >> 4;
    int nidx[4], hwb[4];
#pragma unroll
    for (int fn = 0; fn < 4; ++fn) {
        int sb = s0 + wn * 64 + fn * 16;
        nidx[fn] = sb / HW; hwb[fn] = sb % HW;
    }
#pragma unroll
    for (int fm = 0; fm < 4; ++fm)
#pragma unroll
        for (int r = 0; r < 4; ++r) {
            const int o = bo + wm * 64 + fm * 16 + l4 * 4 + r;
            const float bvs = Bias[o];
#pragma unroll
            for (int fn = 0; fn < 4; ++fn)
                Out[(size_t)nidx[fn] * (OUT_C * HW) + o * HW + hwb[fn] + ln15] = acc[fm][fn][r] + bvs;
        }
}

extern "C" void kernel_launch(void* const* d_in, const int* in_sizes, int n_in,
                              void* d_out, int out_size, void* d_ws, size_t ws_size,
                              hipStream_t stream) {
    const float* x    = (const float*)d_in[0];
    const float* w    = (const float*)d_in[1];
    const float* bias = (const float*)d_in[2];
    float* out = (float*)d_out;

    if (ws_size >= WS_NEEDED) {
        char* xt = (char*)d_ws;
        char* wb = (char*)d_ws + XT_BYTES;
        conv_pre<<<512 + 1568, 256, 0, stream>>>(x, w, (u32x4*)xt, (u32x4*)wb);
        gemm8<<<392, 512, 0, stream>>>(wb, xt, bias, out);
    } else {
        dim3 grid(NHW / BN, OUT_C / BM);
        conv1x1_fallback<<<grid, 256, 0, stream>>>(x, w, bias, out);
    }
}

// Round 5
// 101.525 us; speedup vs baseline: 1.7458x; 1.0323x over previous
//
#include <hip/hip_runtime.h>

// SparseConv1x1 == GEMM: C[o,s] = W[o,:] . X[:,s] + b[o], s = n*784+hw
// M=1024, N=25088, K=1024, fp32 in/out, bf16 MFMA compute.
// Round 5: revert to proven 2-phase 128x128 gemm_k (850 TF) w/ occupancy bump;
// keep merged conv_pre prepass. 8-phase abandoned (2 strikes, lockstep-wait-bound).

#define IN_C   1024
#define OUT_C  1024
#define HW     784
#define NB     32
#define NHW    (NB * HW)                     // 25088
#define XT_BYTES ((size_t)NHW * IN_C * 2)    // 51,380,224
#define WB_BYTES ((size_t)OUT_C * IN_C * 2)  // 2,097,152
#define WS_NEEDED (XT_BYTES + WB_BYTES)

typedef __bf16 bf16x8 __attribute__((ext_vector_type(8)));
typedef float  f32x4  __attribute__((ext_vector_type(4)));
typedef unsigned int u32x4 __attribute__((ext_vector_type(4)));

__device__ __forceinline__ unsigned int bfbits(float f) {
    unsigned int u = __float_as_uint(f);
    return (u + 0x8000u) >> 16;              // round-half-up fp32->bf16
}
__device__ __forceinline__ unsigned int packpair(float lo, float hi) {
    return bfbits(lo) | (bfbits(hi) << 16);
}
__device__ __forceinline__ void glds16(const void* g, void* l) {
    __builtin_amdgcn_global_load_lds(
        (const __attribute__((address_space(1))) void*)g,
        (__attribute__((address_space(3))) void*)l, 16, 0, 0);
}

// ---------- combined pre-pass: blocks [0,512) convert W, [512,2080) transpose x ----
#define XPAD 1040
__global__ __launch_bounds__(256)
void conv_pre(const float* __restrict__ X, const float* __restrict__ W,
              u32x4* __restrict__ Xt, u32x4* __restrict__ Wb)
{
    __shared__ unsigned short T[16 * XPAD];   // 33,280 B (x-path only)
    const int t = threadIdx.x;

    if (blockIdx.x < 512) {
        // W [1024][1024] f32 -> Wb bf16, unit-swizzled
        int gid = blockIdx.x * 256 + t;
        int o = gid >> 7;
        int u = gid & 127;
        const float* p = W + o * 1024 + u * 8;
        f32x4 a = *(const f32x4*)p;
        f32x4 b = *(const f32x4*)(p + 4);
        u32x4 r;
        r.x = packpair(a[0], a[1]); r.y = packpair(a[2], a[3]);
        r.z = packpair(b[0], b[1]); r.w = packpair(b[2], b[3]);
        Wb[o * 128 + (u ^ (o & 7))] = r;
        return;
    }

    // x [32][1024][784] f32 -> Xt [25088 s][1024 k] bf16 swizzled (LDS transpose)
    const int b  = blockIdx.x - 512;          // 1568 = 49 * 32
    const int st = b % 49;
    const int n  = b / 49;

    const int hw4 = t & 3, kr = t >> 2;       // kr 0..63
    const float* base = X + ((size_t)n * IN_C + kr) * HW + st * 16 + hw4 * 4;
#pragma unroll 4
    for (int p = 0; p < 16; ++p) {
        f32x4 v = *(const f32x4*)(base + (size_t)p * 64 * HW);
        const int k = p * 64 + kr;
#pragma unroll
        for (int j = 0; j < 4; ++j)
            T[(hw4 * 4 + j) * XPAD + k] = (unsigned short)bfbits(v[j]);
    }
    __syncthreads();

    const int hw = t >> 4, u0 = t & 15;
    const int s = n * HW + st * 16 + hw;
    u32x4* dst = Xt + (size_t)s * 128;
    const unsigned short* src = &T[hw * XPAD];
#pragma unroll
    for (int j = 0; j < 8; ++j) {
        const int u = u0 + 16 * j;
        u32x4 v = *(const u32x4*)(src + u * 8);
        dst[u ^ (s & 7)] = v;
    }
}

// ---------- GEMM: proven 2-phase, 128x128 tile, BK=64, glds staging ----------
__global__ __launch_bounds__(256, 4)
void gemm_k(const char* __restrict__ Wb, const char* __restrict__ Xt,
            const float* __restrict__ Bias, float* __restrict__ Out)
{
    __shared__ __align__(16) char lA[128 * 128];  // [row][128B chunk], 16KB
    __shared__ __align__(16) char lB[128 * 128];

    const int t = threadIdx.x, lane = t & 63, wid = t >> 6;
    const int wm = wid >> 1, wn = wid & 1;

    // XCD swizzle: 8 o-blocks of one s-tile contiguous within an XCD
    const int bid = blockIdx.x;                   // 1568 = 8*196
    const int l   = (bid & 7) * 196 + (bid >> 3);
    const int bo  = (l & 7) * 128;
    const int s0  = (l >> 3) * 128;

    // staging: per glds, 8 lanes/row, 8 rows/instr, 4 instrs/wave per tile
    const char* ag = Wb + (size_t)(bo + wid * 32 + (lane >> 3)) * 2048 + (lane & 7) * 16;
    const char* bg = Xt + (size_t)(s0 + wid * 32 + (lane >> 3)) * 2048 + (lane & 7) * 16;
    char* la0 = &lA[(wid * 32) * 128];
    char* lb0 = &lB[(wid * 32) * 128];

    f32x4 acc[4][4];
#pragma unroll
    for (int i = 0; i < 4; ++i)
#pragma unroll
        for (int j = 0; j < 4; ++j) acc[i][j] = 0.0f;

    const int rsel = lane & 15, kg = lane >> 4;

    for (int c = 0; c < 16; ++c) {                // K chunks of 64
        const int cb = c * 128;
#pragma unroll
        for (int i = 0; i < 4; ++i) {
            glds16(ag + (size_t)i * (8 * 2048) + cb, la0 + i * (8 * 128));
            glds16(bg + (size_t)i * (8 * 2048) + cb, lb0 + i * (8 * 128));
        }
        __syncthreads();   // drains vmcnt -> tiles ready (and all waves staged)

#pragma unroll
        for (int kk = 0; kk < 2; ++kk) {
            bf16x8 af[4], bv[4];
#pragma unroll
            for (int fm = 0; fm < 4; ++fm) {
                const int row = wm * 64 + fm * 16 + rsel;
                const int u   = (kk * 4 + kg) ^ (row & 7);
                af[fm] = *(const bf16x8*)&lA[row * 128 + u * 16];
            }
#pragma unroll
            for (int fn = 0; fn < 4; ++fn) {
                const int row = wn * 64 + fn * 16 + rsel;
                const int u   = (kk * 4 + kg) ^ (row & 7);
                bv[fn] = *(const bf16x8*)&lB[row * 128 + u * 16];
            }
#pragma unroll
            for (int fm = 0; fm < 4; ++fm)
#pragma unroll
                for (int fn = 0; fn < 4; ++fn)
                    acc[fm][fn] = __builtin_amdgcn_mfma_f32_16x16x32_bf16(
                        af[fm], bv[fn], acc[fm][fn], 0, 0, 0);
        }
        __syncthreads();   // all reads done before next stage overwrites
    }

    // epilogue: C/D layout col=lane&15, row=(lane>>4)*4+r
    const int ln15 = lane & 15, l4 = lane >> 4;
    int nidx[4], hwb[4];
#pragma unroll
    for (int fn = 0; fn < 4; ++fn) {
        int sb = s0 + wn * 64 + fn * 16;          // 784%16==0 -> same batch per 16-run
        nidx[fn] = sb / HW;
        hwb[fn]  = sb % HW;
    }
#pragma unroll
    for (int fm = 0; fm < 4; ++fm) {
#pragma unroll
        for (int r = 0; r < 4; ++r) {
            const int o = bo + wm * 64 + fm * 16 + l4 * 4 + r;
            const float bvs = Bias[o];
#pragma unroll
            for (int fn = 0; fn < 4; ++fn)
                Out[(size_t)nidx[fn] * (OUT_C * HW) + o * HW + hwb[fn] + ln15] =
                    acc[fm][fn][r] + bvs;
        }
    }
}

// ---------- fallback (round-1 kernel, used only if ws too small) ----------
#define BM 128
#define BN 128
#define LDK 40
__global__ __launch_bounds__(256, 2)
void conv1x1_fallback(const float* __restrict__ X, const float* __restrict__ W,
                      const float* __restrict__ Bias, float* __restrict__ Out)
{
    __shared__ __align__(16) unsigned short lA[BM * LDK];
    __shared__ __align__(16) unsigned short lB[BN * LDK];
    const int t = threadIdx.x, lane = t & 63, wid = t >> 6;
    const int wm = wid >> 1, wn = wid & 1;
    const int s0 = blockIdx.x * BN, bo = blockIdx.y * BM;
    const int kc4 = t & 7, r0 = t >> 3;
    const float* aptr = W + (bo + r0) * IN_C + kc4 * 4;
    const int kp = t & 15, sc = t >> 4;
    const int sglob = s0 + sc * 8;
    const int nbat = sglob / HW, hw0 = sglob % HW;
    const float* bptr = X + nbat * (IN_C * HW) + hw0;
    f32x4 acc[4][4];
#pragma unroll
    for (int i = 0; i < 4; ++i)
#pragma unroll
        for (int j = 0; j < 4; ++j) acc[i][j] = 0.0f;
    for (int k0 = 0; k0 < IN_C; k0 += 32) {
        f32x4 a[4];
#pragma unroll
        for (int i = 0; i < 4; ++i) a[i] = *(const f32x4*)(aptr + (i * 32) * IN_C + k0);
        const float* bp = bptr + (k0 + 2 * kp) * HW;
        f32x4 be0 = *(const f32x4*)(bp), be1 = *(const f32x4*)(bp + 4);
        f32x4 bo0 = *(const f32x4*)(bp + HW), bo1 = *(const f32x4*)(bp + HW + 4);
        __syncthreads();
#pragma unroll
        for (int i = 0; i < 4; ++i) {
            unsigned int w0 = packpair(a[i][0], a[i][1]);
            unsigned int w1 = packpair(a[i][2], a[i][3]);
            unsigned long long pq = ((unsigned long long)w1 << 32) | w0;
            *(unsigned long long*)&lA[(r0 + 32 * i) * LDK + kc4 * 4] = pq;
        }
#pragma unroll
        for (int c2 = 0; c2 < 2; ++c2) {
            const f32x4 ve = (c2 == 0) ? be0 : be1;
            const f32x4 vo = (c2 == 0) ? bo0 : bo1;
#pragma unroll
            for (int j = 0; j < 4; ++j)
                *(unsigned int*)&lB[(sc * 8 + c2 * 4 + j) * LDK + 2 * kp] = packpair(ve[j], vo[j]);
        }
        __syncthreads();
        bf16x8 af[4], bfr[4];
        const int rsel = lane & 15, kgp = (lane >> 4) * 8;
#pragma unroll
        for (int fm = 0; fm < 4; ++fm)
            af[fm] = *(const bf16x8*)&lA[(wm * 64 + fm * 16 + rsel) * LDK + kgp];
#pragma unroll
        for (int fn = 0; fn < 4; ++fn)
            bfr[fn] = *(const bf16x8*)&lB[(wn * 64 + fn * 16 + rsel) * LDK + kgp];
#pragma unroll
        for (int fm = 0; fm < 4; ++fm)
#pragma unroll
            for (int fn = 0; fn < 4; ++fn)
                acc[fm][fn] = __builtin_amdgcn_mfma_f32_16x16x32_bf16(af[fm], bfr[fn], acc[fm][fn], 0, 0, 0);
    }
    const int ln15 = lane & 15, l4 = lane >> 4;
    int nidx[4], hwb[4];
#pragma unroll
    for (int fn = 0; fn < 4; ++fn) {
        int sb = s0 + wn * 64 + fn * 16;
        nidx[fn] = sb / HW; hwb[fn] = sb % HW;
    }
#pragma unroll
    for (int fm = 0; fm < 4; ++fm)
#pragma unroll
        for (int r = 0; r < 4; ++r) {
            const int o = bo + wm * 64 + fm * 16 + l4 * 4 + r;
            const float bvs = Bias[o];
#pragma unroll
            for (int fn = 0; fn < 4; ++fn)
                Out[(size_t)nidx[fn] * (OUT_C * HW) + o * HW + hwb[fn] + ln15] = acc[fm][fn][r] + bvs;
        }
}

extern "C" void kernel_launch(void* const* d_in, const int* in_sizes, int n_in,
                              void* d_out, int out_size, void* d_ws, size_t ws_size,
                              hipStream_t stream) {
    const float* x    = (const float*)d_in[0];
    const float* w    = (const float*)d_in[1];
    const float* bias = (const float*)d_in[2];
    float* out = (float*)d_out;

    if (ws_size >= WS_NEEDED) {
        char* xt = (char*)d_ws;
        char* wb = (char*)d_ws + XT_BYTES;
        conv_pre<<<512 + 1568, 256, 0, stream>>>(x, w, (u32x4*)xt, (u32x4*)wb);
        gemm_k<<<1568, 256, 0, stream>>>(wb, xt, bias, out);
    } else {
        dim3 grid(NHW / BN, OUT_C / BM);
        conv1x1_fallback<<<grid, 256, 0, stream>>>(x, w, bias, out);
    }
}